// Round 4
// baseline (303.172 us; speedup 1.0000x reference)
//
#include <hip/hip_runtime.h>
#include <math.h>

// Attention: out = softmax((q@Wq+bq)(k@Wk+bk)^T / sqrt(D)) @ (v@Wv+bv)
// B=4, S=2048, D=1024, fp32 in/out.
//
// Round 10: register-pipelined single-barrier GEMM schedule.
// r9 post-mortem: prefetch depth didn't matter (67us, MfmaUtil 30%) because
// the phase structure [reads -> SBAR -> lgkm(0) -> MFMA -> SBAR] serializes
// the LDS pipe (~256-768cyc/phase) against the MFMA pipe (~155cyc/phase).
// Fix: read NEXT phase's fragments into a 2nd register set before current
// MFMA, guarded by counted lgkmcnt(8) -> LDS drain overlaps MFMA. One
// barrier per phase. Same 128x256 tile / 3 LDS bufs / swizzle / grids.
// Schedule (2 phases per K-tile t; bufs b0=tile t, b1=t+1, b2=dead t-1):
//   ph0: read nxt<-G1(t)[b0,k1]; stage G0(t+2)->b2; lgkm(8); MFMA(cur);
//        VMW(6|3); SBAR
//   ph1: read cur<-G0(t+1)[b1,k0]; stage G1(t+2)->b2; lgkm(8); MFMA(nxt);
//        VMW(6|0); SBAR; rotate(b0<-b1<-b2<-b0)
// vmcnt ledger (3 loads/group):
//   end-ph0(t) guards G0(t+1): newer = G1(t+1)@(t-1,ph1), G0(t+2)@(t,ph0)
//     -> 6 if t+2<nt, 3 if t==nt-2; skipped if t==nt-1
//   end-ph1(t) guards G1(t+1): newer = G0(t+2),G1(t+2) -> 6 if t+2<nt,
//     0 if t==nt-2
//   prologue: stage G0(0) G1(0) G0(1) G1(1); VMW(9); SBAR; read cur<-G0(0);
//     VMW(6); SBAR
// Overwrite hazard: b2's old data last read at (t-1,ph0) [drained by
// lgkm(8)@(t-1,ph1)] -> SBAR@end(t-1,ph1) precedes stage@(t,ph0). Safe.
// lgkm(8) counted: all lgkm ops are ds_read_b128 (in-order); 8 newer reads
// = next phase's fragments. sched_barrier(0) after each wait (rule #18).

using short8  = __attribute__((ext_vector_type(8))) short;
using floatx4 = __attribute__((ext_vector_type(4))) float;

// round-half-up bf16 (2 VALU; differs from RNE only on exact ties)
__device__ __forceinline__ unsigned short f2bf(float f) {
    union { float f; unsigned u; } x; x.f = f;
    return (unsigned short)((x.u + 0x8000u) >> 16);
}

__device__ __forceinline__ void gload_lds16(const unsigned short* g, unsigned short* l) {
    __builtin_amdgcn_global_load_lds(
        (const __attribute__((address_space(1))) unsigned int*)g,
        (__attribute__((address_space(3))) unsigned int*)l, 16, 0, 0);
}

#define SBAR    __builtin_amdgcn_s_barrier()
#define SCHEDB  __builtin_amdgcn_sched_barrier(0)
#define LGKM(n) asm volatile("s_waitcnt lgkmcnt(" #n ")" ::: "memory")
#define VMW(n)  asm volatile("s_waitcnt vmcnt(" #n ")" ::: "memory")

// ---------------- prep: qkv conv (blocks 0..24575) + W transpose (24576..27647) ----
__global__ __launch_bounds__(256) void prep(
    const float* __restrict__ q, const float* __restrict__ k, const float* __restrict__ v,
    const float* __restrict__ W0, const float* __restrict__ W1, const float* __restrict__ W2,
    unsigned short* __restrict__ qkvbf, unsigned short* __restrict__ Wt)
{
    __shared__ float tile[32][33];
    const int id = blockIdx.x;
    const int t  = threadIdx.x;
    if (id < 24576) {
        const int z  = id >> 13;
        const int xb = id & 8191;
        const float* x = (z == 0) ? q : (z == 1) ? k : v;
        const size_t i = ((size_t)xb * 256 + t) * 4;
        const float4 a = *(const float4*)(x + i);
        ushort4 p = { f2bf(a.x), f2bf(a.y), f2bf(a.z), f2bf(a.w) };
        *(ushort4*)(qkvbf + (size_t)z * 8192 * 1024 + i) = p;
    } else {
        const int idt = id - 24576;
        const int z  = idt >> 10;
        const int r  = idt & 1023;
        const int bx = (r & 31) * 32;
        const int by = (r >> 5) * 32;
        const float* W = (z == 0) ? W0 : (z == 1) ? W1 : W2;
        unsigned short* o = Wt + (size_t)z * 1024 * 1024;
        const int tx = t & 31;
        const int ty = (t >> 5) * 4;
        #pragma unroll
        for (int rr = 0; rr < 4; ++rr)
            tile[ty + rr][tx] = W[(size_t)(by + ty + rr) * 1024 + bx + tx];
        __syncthreads();
        #pragma unroll
        for (int rr = 0; rr < 4; ++rr)
            o[(size_t)(bx + ty + rr) * 1024 + by + tx] = f2bf(tile[tx][ty + rr]);
    }
}

// ======== register-pipelined, triple-buffered 128x256 GEMM (bf16) ========
// LDS map (shorts): buf b at b*24576; A-kh at kh*4096 [128][32];
//   B-kh at 8192 + kh*8192 [256][32]. Swizzle: 16B slot s of row r holds
//   global slot s ^ ((r>>1)&3).

#define STAGE_A(bb, kh, tt) do { \
    gload_lds16(gA + (size_t)srowA * lda + (tt) * 64 + (kh) * 32 + scol, \
                lds + (bb) * 24576 + (kh) * 4096 + t512 * 8); \
} while (0)

#define STAGE_B(bb, kh, tt) do { \
    const unsigned short* s_ = gB + (size_t)srowA * ldb + (tt) * 64 + (kh) * 32 + scol; \
    unsigned short* d_ = lds + (bb) * 24576 + 8192 + (kh) * 8192 + t512 * 8; \
    gload_lds16(s_, d_); \
    gload_lds16(s_ + (size_t)128 * ldb, d_ + 4096); \
} while (0)

#define LDSA(bb, kh, i) (*(const short8*)&lds[(bb) * 24576 + (kh) * 4096 + (arow + (i) * 16) * 32 + rslot])
#define LDSB(bb, kh, j) (*(const short8*)&lds[(bb) * 24576 + 8192 + (kh) * 8192 + (brow + (j) * 16) * 32 + rslot])

#define READ8(dA, dB, bb, kh) do { \
    _Pragma("unroll") \
    for (int j_ = 0; j_ < 4; ++j_) dB[j_] = LDSB(bb, kh, j_); \
    _Pragma("unroll") \
    for (int i_ = 0; i_ < 4; ++i_) dA[i_] = LDSA(bb, kh, i_); \
} while (0)

#define MFMA16(Af, Bf) do { \
    __builtin_amdgcn_s_setprio(1); \
    _Pragma("unroll") \
    for (int i_ = 0; i_ < 4; ++i_) \
        _Pragma("unroll") \
        for (int j_ = 0; j_ < 4; ++j_) \
            acc[i_][j_] = __builtin_amdgcn_mfma_f32_16x16x32_bf16( \
                Af[i_], Bf[j_], acc[i_][j_], 0, 0, 0); \
    __builtin_amdgcn_s_setprio(0); \
} while (0)

__device__ __forceinline__ void gemm_pipe(
    const unsigned short* __restrict__ gA, int lda,
    const unsigned short* __restrict__ gB, int ldb,
    int nt, unsigned short* lds, floatx4 (&acc)[4][4])
{
    const int t512 = threadIdx.x;
    const int lane = t512 & 63;
    const int wave = t512 >> 6;
    const int wr   = wave >> 2;          // 0..1 (M)
    const int wc   = wave & 3;           // 0..3 (N)
    const int l15  = lane & 15;
    const int quad = lane >> 4;
    const int srowA = t512 >> 2;                                 // staging row 0..127
    const int scol  = ((t512 & 3) ^ ((t512 >> 3) & 3)) * 8;      // pre-swizzled global slot
    const int rslot = (quad ^ ((l15 >> 1) & 3)) * 8;             // swizzled read slot
    const int arow  = wr * 64 + l15;
    const int brow  = wc * 64 + l15;

    short8 cA[4], cB[4], nA[4], nB[4];

    // prologue: stage K-tiles 0,1; read cur = G0(0)
    STAGE_A(0, 0, 0); STAGE_B(0, 0, 0);
    STAGE_A(0, 1, 0); STAGE_B(0, 1, 0);
    STAGE_A(1, 0, 1); STAGE_B(1, 0, 1);
    STAGE_A(1, 1, 1); STAGE_B(1, 1, 1);
    VMW(9);            // G0(0) landed (9 newer)
    SBAR;
    READ8(cA, cB, 0, 0);
    VMW(6);            // G1(0) landed (6 newer)
    SBAR;

    int b0 = 0, b1 = 1, b2 = 2;
    for (int t = 0; t < nt; ++t) {
        // ---- phase 0: MFMA cur=G0(t); read nxt<-G1(t); stage G0(t+2)
        READ8(nA, nB, b0, 1);
        if (t + 2 < nt) { STAGE_A(b2, 0, t + 2); STAGE_B(b2, 0, t + 2); }
        LGKM(8); SCHEDB;          // cur drained; nxt's 8 reads in flight
        MFMA16(cA, cB);
        if (t + 1 < nt) {
            if (t + 2 < nt) { VMW(6); } else { VMW(3); }   // G0(t+1) landed
            SBAR;
            // ---- phase 1: MFMA nxt=G1(t); read cur<-G0(t+1); stage G1(t+2)
            READ8(cA, cB, b1, 0);
            if (t + 2 < nt) { STAGE_A(b2, 1, t + 2); STAGE_B(b2, 1, t + 2); }
            LGKM(8); SCHEDB;      // nxt drained; cur's 8 reads in flight
            MFMA16(nA, nB);
            if (t + 2 < nt) { VMW(6); } else { VMW(0); }   // G1(t+1) landed
            SBAR;
        } else {
            // tail: t == nt-1, no further reads/stages
            LGKM(0); SCHEDB;
            MFMA16(nA, nB);
        }
        const int tmp = b0; b0 = b1; b1 = b2; b2 = tmp;
    }
}

#define EPI_IDS                                   \
    const int tt   = threadIdx.x;                 \
    const int lane = tt & 63;                     \
    const int wave = tt >> 6;                     \
    const int wr   = wave >> 2;                   \
    const int wc   = wave & 3;                    \
    const int l15  = lane & 15;                   \
    const int quad = lane >> 4;

// ---------------- fused QKV projection, 768 blocks, XCD-swizzled ----
__global__ __launch_bounds__(512) void proj8(
    const unsigned short* __restrict__ Abf,
    const unsigned short* __restrict__ Wt,
    const float* __restrict__ bq, const float* __restrict__ bk, const float* __restrict__ bv,
    unsigned short* __restrict__ Qp, unsigned short* __restrict__ Kp,
    unsigned short* __restrict__ Vpt)
{
    __shared__ __attribute__((aligned(16))) unsigned short lds[73728];
    const int id = blockIdx.x;
    const int g  = (id & 7) * 96 + (id >> 3);    // 768 = 8 XCDs x 96
    const int z  = g >> 8;                       // 0..2
    const int r  = g & 255;
    const int m0 = (r >> 2) * 128;
    const int n0 = (r & 3) * 256;

    const unsigned short* gA = Abf + (size_t)z * 8192 * 1024 + (size_t)m0 * 1024;
    const unsigned short* gB = Wt  + (size_t)z * 1024 * 1024 + (size_t)n0 * 1024;

    floatx4 acc[4][4] = {};
    gemm_pipe(gA, 1024, gB, 1024, 16, lds, acc);

    EPI_IDS
    const float* bias = (z == 0) ? bq : (z == 1) ? bk : bv;
    #pragma unroll
    for (int j = 0; j < 4; ++j) {
        const int col = n0 + wc * 64 + j * 16 + l15;
        const float bv_ = bias[col];
        #pragma unroll
        for (int i = 0; i < 4; ++i) {
            const int row = m0 + wr * 64 + i * 16 + quad * 4;
            if (z < 2) {
                unsigned short* C = (z == 0) ? Qp : Kp;
                #pragma unroll
                for (int r2 = 0; r2 < 4; ++r2)
                    C[(size_t)(row + r2) * 1024 + col] = f2bf(acc[i][j][r2] + bv_);
            } else {
                ushort4 p = { f2bf(acc[i][j][0] + bv_), f2bf(acc[i][j][1] + bv_),
                              f2bf(acc[i][j][2] + bv_), f2bf(acc[i][j][3] + bv_) };
                *(ushort4*)&Vpt[(size_t)col * 8192 + row] = p;
            }
        }
    }
}

// ---------------- scores: Pexp = exp(Qp @ Kp^T / 32) bf16 + row sums ----
__global__ __launch_bounds__(512) void scores8(
    const unsigned short* __restrict__ Qp,
    const unsigned short* __restrict__ Kp,
    unsigned short* __restrict__ Pexp,
    float* __restrict__ rowsum)
{
    __shared__ __attribute__((aligned(16))) unsigned short lds[73728];
    const int id = blockIdx.x;
    const int g  = (id & 7) * 64 + (id >> 3);    // 512 blocks
    const int z  = g >> 7;
    const int r  = g & 127;
    const int m0 = (r >> 3) * 128;
    const int n0 = (r & 7) * 256;

    const unsigned short* gA = Qp + (size_t)z * 2048 * 1024 + (size_t)m0 * 1024;
    const unsigned short* gB = Kp + (size_t)z * 2048 * 1024 + (size_t)n0 * 1024;

    floatx4 acc[4][4] = {};
    gemm_pipe(gA, 1024, gB, 1024, 16, lds, acc);

    EPI_IDS
    unsigned short* P = Pexp + (size_t)z * 2048 * 2048;
    float* rs = rowsum + (size_t)z * 2048;
    #pragma unroll
    for (int i = 0; i < 4; ++i) {
        const int rowb = m0 + wr * 64 + i * 16 + quad * 4;
        float sm[4] = {0.f, 0.f, 0.f, 0.f};
        #pragma unroll
        for (int j = 0; j < 4; ++j) {
            const int col = n0 + wc * 64 + j * 16 + l15;
            #pragma unroll
            for (int r2 = 0; r2 < 4; ++r2) {
                const float p = __expf(acc[i][j][r2] * 0.03125f);
                sm[r2] += p;
                P[(size_t)(rowb + r2) * 2048 + col] = f2bf(p);
            }
        }
        #pragma unroll
        for (int r2 = 0; r2 < 4; ++r2) {
            float s = sm[r2];
            s += __shfl_xor(s, 1);
            s += __shfl_xor(s, 2);
            s += __shfl_xor(s, 4);
            s += __shfl_xor(s, 8);
            if (l15 == 0)
                atomicAdd(&rs[rowb + r2], s);
        }
    }
}

// ---------------- PV: out = (Pexp @ Vpt^T) / rowsum, fp32 ----------------
__global__ __launch_bounds__(512) void pv8(
    const unsigned short* __restrict__ Pexp,
    const unsigned short* __restrict__ Vpt,
    const float* __restrict__ rowsum,
    float* __restrict__ out)
{
    __shared__ __attribute__((aligned(16))) unsigned short lds[73728];
    const int id = blockIdx.x;
    const int g  = (id & 7) * 32 + (id >> 3);    // 256 blocks
    const int z  = g >> 6;
    const int r  = g & 63;
    const int m0 = (r >> 2) * 128;
    const int n0 = (r & 3) * 256;

    const unsigned short* gA = Pexp + (size_t)z * 2048 * 2048 + (size_t)m0 * 2048;
    const unsigned short* gB = Vpt  + (size_t)n0 * 8192 + (size_t)z * 2048;

    floatx4 acc[4][4] = {};
    gemm_pipe(gA, 2048, gB, 8192, 32, lds, acc);

    EPI_IDS
    const float* rs = rowsum + (size_t)z * 2048;
    float* C = out + (size_t)z * 2048 * 1024;
    #pragma unroll
    for (int i = 0; i < 4; ++i) {
        const int rowb = m0 + wr * 64 + i * 16 + quad * 4;
        float inv[4];
        #pragma unroll
        for (int r2 = 0; r2 < 4; ++r2) inv[r2] = 1.0f / rs[rowb + r2];
        #pragma unroll
        for (int j = 0; j < 4; ++j) {
            const int col = n0 + wc * 64 + j * 16 + l15;
            #pragma unroll
            for (int r2 = 0; r2 < 4; ++r2)
                C[(size_t)(rowb + r2) * 1024 + col] = acc[i][j][r2] * inv[r2];
        }
    }
}

extern "C" void kernel_launch(void* const* d_in, const int* in_sizes, int n_in,
                              void* d_out, int out_size, void* d_ws, size_t ws_size,
                              hipStream_t stream)
{
    const float* q  = (const float*)d_in[0];
    const float* k  = (const float*)d_in[1];
    const float* v  = (const float*)d_in[2];
    const float* Wq = (const float*)d_in[3];
    const float* bq = (const float*)d_in[4];
    const float* Wk = (const float*)d_in[5];
    const float* bk = (const float*)d_in[6];
    const float* Wv = (const float*)d_in[7];
    const float* bv = (const float*)d_in[8];
    float* out = (float*)d_out;

    const int Bn = 4, S = 2048;

    char* w = (char*)d_ws;
    unsigned short* Wt     = (unsigned short*)(w);                  // 6 MB
    unsigned short* Qp     = (unsigned short*)(w + (6u << 20));     // 16 MB [8192,1024]
    unsigned short* Kp     = (unsigned short*)(w + (22u << 20));    // 16 MB
    unsigned short* Vpt    = (unsigned short*)(w + (38u << 20));    // 16 MB [1024,8192]
    unsigned short* qkvbf  = (unsigned short*)(w + (54u << 20));    // 48 MB (dead after proj)
    unsigned short* Pexp   = (unsigned short*)(w + (54u << 20));    // 32 MB (over dead qkvbf)
    float*          rowsum = (float*)(w + (86u << 20));             // 32 KB

    // zero the row-sum accumulators (ws is poisoned before each call)
    hipMemsetAsync(rowsum, 0, (size_t)Bn * S * sizeof(float), stream);

    // prep: qkv fp32->bf16 + W->W^T bf16
    prep<<<dim3(27648), dim3(256), 0, stream>>>(q, k, v, Wq, Wk, Wv, qkvbf, Wt);

    // fused projections (register-pipelined 128x256): -> Qp, Kp, Vpt^T
    proj8<<<dim3(768), dim3(512), 0, stream>>>(qkvbf, Wt, bq, bk, bv, Qp, Kp, Vpt);

    // Pexp = exp(Qp @ Kp^T / 32) bf16 + rowsum atomics
    scores8<<<dim3(512), dim3(512), 0, stream>>>(Qp, Kp, Pexp, rowsum);

    // out = (Pexp @ Vpt^T) / rowsum
    pv8<<<dim3(256), dim3(512), 0, stream>>>(Pexp, Vpt, rowsum, out);
}